// Round 5
// baseline (128.102 us; speedup 1.0000x reference)
//
#include <hip/hip_runtime.h>
#include <math.h>

// PRNN J2 plane-strain elastoplasticity scan.
// B=16384, T=128, F=3, MATPTS=16 (P=262144), O=3.
// R5: ILP-2 — each thread runs TWO independent packed chains (points l,l+8 of
// two different batches). 8 lanes per batch, 64 batches per 256-thread block,
// 256 blocks = 1 block/CU, 1 wave/SIMD. Weights (batch-independent) shared
// across chains. 6-output fused-DPP 8-lane butterfly, hazard-safe by 6-way
// interleave.

#define BLOCK 256
#define BPB 64              // batches per block (32 groups x 2 batches)
#define TSTEPS 128
#define ROWF (TSTEPS * 3)   // 384 floats per batch row
#define ROWP 388            // padded stride, 16B-aligned

typedef float v2 __attribute__((ext_vector_type(2)));

static __device__ __forceinline__ v2 vfma(v2 a, v2 b, v2 c) {
    return __builtin_elementwise_fma(a, b, c);
}
static __device__ __forceinline__ v2 vmax(v2 a, v2 b) {
    return __builtin_elementwise_max(a, b);
}

// 8-lane butterfly sum of SIX scalars via fused DPP adds. Stages:
// quad_perm xor1, quad_perm xor2 (intra-quad), row_half_mirror (cross-quad).
// 6-way interleave => 5 instructions between a register's consecutive stages
// (hazard needs 2). s_nop 1 covers the entry hazard from producer folds.
#define DPP_BFLY6(a, b, c, d, e, f)                                              \
  asm volatile(                                                                  \
    "s_nop 1\n\t"                                                                \
    "v_add_f32_dpp %0, %0, %0 quad_perm:[1,0,3,2] row_mask:0xf bank_mask:0xf\n\t"\
    "v_add_f32_dpp %1, %1, %1 quad_perm:[1,0,3,2] row_mask:0xf bank_mask:0xf\n\t"\
    "v_add_f32_dpp %2, %2, %2 quad_perm:[1,0,3,2] row_mask:0xf bank_mask:0xf\n\t"\
    "v_add_f32_dpp %3, %3, %3 quad_perm:[1,0,3,2] row_mask:0xf bank_mask:0xf\n\t"\
    "v_add_f32_dpp %4, %4, %4 quad_perm:[1,0,3,2] row_mask:0xf bank_mask:0xf\n\t"\
    "v_add_f32_dpp %5, %5, %5 quad_perm:[1,0,3,2] row_mask:0xf bank_mask:0xf\n\t"\
    "v_add_f32_dpp %0, %0, %0 quad_perm:[2,3,0,1] row_mask:0xf bank_mask:0xf\n\t"\
    "v_add_f32_dpp %1, %1, %1 quad_perm:[2,3,0,1] row_mask:0xf bank_mask:0xf\n\t"\
    "v_add_f32_dpp %2, %2, %2 quad_perm:[2,3,0,1] row_mask:0xf bank_mask:0xf\n\t"\
    "v_add_f32_dpp %3, %3, %3 quad_perm:[2,3,0,1] row_mask:0xf bank_mask:0xf\n\t"\
    "v_add_f32_dpp %4, %4, %4 quad_perm:[2,3,0,1] row_mask:0xf bank_mask:0xf\n\t"\
    "v_add_f32_dpp %5, %5, %5 quad_perm:[2,3,0,1] row_mask:0xf bank_mask:0xf\n\t"\
    "v_add_f32_dpp %0, %0, %0 row_half_mirror row_mask:0xf bank_mask:0xf\n\t"    \
    "v_add_f32_dpp %1, %1, %1 row_half_mirror row_mask:0xf bank_mask:0xf\n\t"    \
    "v_add_f32_dpp %2, %2, %2 row_half_mirror row_mask:0xf bank_mask:0xf\n\t"    \
    "v_add_f32_dpp %3, %3, %3 row_half_mirror row_mask:0xf bank_mask:0xf\n\t"    \
    "v_add_f32_dpp %4, %4, %4 row_half_mirror row_mask:0xf bank_mask:0xf\n\t"    \
    "v_add_f32_dpp %5, %5, %5 row_half_mirror row_mask:0xf bank_mask:0xf"        \
    : "+v"(a), "+v"(b), "+v"(c), "+v"(d), "+v"(e), "+v"(f))

struct St { v2 p0, p1, p2, p3, yld; };

__device__ __forceinline__ void j2_step(const v2 (&w1p)[3][3], const v2 (&w2p)[3][3],
                                        float x0s, float x1s, float x2s, St& S,
                                        float& o0, float& o1, float& o2)
{
    constexpr float MU    = (float)(3130.0 / (2.0 * (1.0 + 0.37)));
    constexpr float LAM   = (float)(3130.0 * 0.37 / ((1.0 + 0.37) * (1.0 - 2.0 * 0.37)));
    constexpr float H_ISO = 300.0f;
    const float TWO_MU  = 2.0f * MU;
    const float K3MU    = 3.0f * MU;
    const float INV_DEN = 1.0f / (3.0f * MU + H_ISO);
    const float KBULK   = LAM + TWO_MU * (1.0f / 3.0f);
    const float C_Q2    = 6.0f * MU * MU;

    const v2 x0 = {x0s, x0s}, x1 = {x1s, x1s}, x2 = {x2s, x2s};
    const v2 e0 = vfma(w1p[0][0], x0, vfma(w1p[0][1], x1, w1p[0][2] * x2));
    const v2 e1 = vfma(w1p[1][0], x0, vfma(w1p[1][1], x1, w1p[1][2] * x2));
    const v2 e2 = vfma(w1p[2][0], x0, vfma(w1p[2][1], x1, w1p[2][2] * x2));
    const v2 ee_xx = e0 - S.p0;
    const v2 ee_yy = e1 - S.p1;
    const v2 ee_xy = 0.5f * e2 - S.p3;
    const v2 tr = (ee_xx + ee_yy) - S.p2;
    const v2 c3 = tr * (1.0f / 3.0f);
    const v2 exd = ee_xx - c3;
    const v2 eyd = ee_yy - c3;
    const v2 ezd = -S.p2 - c3;
    v2 u = exd * exd;
    u = vfma(eyd, eyd, u);
    u = vfma(ezd, ezd, u);
    u = vfma(ee_xy * ee_xy, (v2){2.0f, 2.0f}, u);
    const v2 q2 = vmax(C_Q2 * u, (v2){1e-24f, 1e-24f});
    v2 rq;
    rq.x = __builtin_amdgcn_rsqf(q2.x);
    rq.y = __builtin_amdgcn_rsqf(q2.y);
    const v2 q = q2 * rq;
    const v2 dgam = vmax(q - S.yld, (v2){0.0f, 0.0f}) * INV_DEN;
    S.yld = vfma((v2){H_ISO, H_ISO}, dgam, S.yld);
    const v2 k   = (K3MU * dgam) * rq;
    const v2 omk = 1.0f - k;
    const v2 pm  = KBULK * tr;
    const v2 s0 = vfma(TWO_MU * exd, omk, pm);
    const v2 s1 = vfma(TWO_MU * eyd, omk, pm);
    const v2 s2 = (TWO_MU * ee_xy) * omk;
    S.p0 = vfma(k, exd, S.p0);
    S.p1 = vfma(k, eyd, S.p1);
    S.p2 = vfma(k, ezd, S.p2);
    S.p3 = vfma(k, ee_xy, S.p3);
    v2 r0 = vfma(w2p[0][0], s0, vfma(w2p[0][1], s1, w2p[0][2] * s2));
    v2 r1 = vfma(w2p[1][0], s0, vfma(w2p[1][1], s1, w2p[1][2] * s2));
    v2 r2 = vfma(w2p[2][0], s0, vfma(w2p[2][1], s1, w2p[2][2] * s2));
    o0 = r0.x + r0.y;
    o1 = r1.x + r1.y;
    o2 = r2.x + r2.y;
}

__global__ __launch_bounds__(BLOCK, 1)
void prnn_j2_kernel(const float* __restrict__ x,
                    const float* __restrict__ W1,
                    const float* __restrict__ W2,
                    float* __restrict__ out)
{
    constexpr float SIG_Y = 64.8f;
    // +12 floats: harmless one-block-over prefetch on the last iteration
    __shared__ float xs[BPB * ROWP + 12];

    const int tid = threadIdx.x;
    const int g   = tid >> 3;       // group 0..31 -> batches (2g, 2g+1)
    const int l   = tid & 7;        // lane in 8-group; points (l, l+8)
    const int blockBase = blockIdx.x * (BPB * ROWF);

    // ---- stage x into LDS (coalesced float4 global reads) ----
    {
        const float4* xg = (const float4*)(x + blockBase);
        for (int i4 = tid; i4 < BPB * ROWF / 4; i4 += BLOCK) {
            int b  = i4 / (ROWF / 4);
            int r4 = i4 - b * (ROWF / 4);
            ((float4*)(xs + b * ROWP))[r4] = xg[i4];
        }
    }

    // ---- packed per-thread weights (batch-independent, shared by chains) ----
    const int pa = l, pb = l + 8;
    v2 w1p[3][3], w2p[3][3];
    #pragma unroll
    for (int c = 0; c < 3; ++c)
        #pragma unroll
        for (int f = 0; f < 3; ++f) {
            w1p[c][f].x = W1[(3 * pa + c) * 3 + f];
            w1p[c][f].y = W1[(3 * pb + c) * 3 + f];
        }
    #pragma unroll
    for (int o = 0; o < 3; ++o)
        #pragma unroll
        for (int c = 0; c < 3; ++c) {
            float wa = W2[o * 48 + 3 * pa + c];
            float wb = W2[o * 48 + 3 * pb + c];
            w2p[o][c].x = fmaxf(wa, 0.0f) + log1pf(expf(-fabsf(wa)));
            w2p[o][c].y = fmaxf(wb, 0.0f) + log1pf(expf(-fabsf(wb)));
        }

    __syncthreads();

    St SA, SB;
    SA.p0 = SA.p1 = SA.p2 = SA.p3 = (v2){0.f, 0.f};
    SB.p0 = SB.p1 = SB.p2 = SB.p3 = (v2){0.f, 0.f};
    SA.yld = SB.yld = (v2){SIG_Y, SIG_Y};

    float* xrowA = &xs[(2 * g + 0) * ROWP];
    float* xrowB = &xs[(2 * g + 1) * ROWP];
    const float4* xvA = (const float4*)xrowA;
    const float4* xvB = (const float4*)xrowB;

    // per-thread write slot: lanes 0..2 write batch A comps, 4..6 batch B
    const int comp   = l & 3;            // 0..3 (3 inactive)
    const bool wact  = comp < 3;
    const bool isA   = l < 4;
    float* wbase = (isA ? xrowA : xrowB) + comp;

    float4 A0 = xvA[0], A1 = xvA[1], A2 = xvA[2];
    float4 B0 = xvB[0], B1 = xvB[1], B2 = xvB[2];

    for (int tb = 0; tb < TSTEPS / 4; ++tb) {
        // prefetch next 4-step block (last iter over-reads into pad)
        float4 An0 = xvA[3 * tb + 3], An1 = xvA[3 * tb + 4], An2 = xvA[3 * tb + 5];
        float4 Bn0 = xvB[3 * tb + 3], Bn1 = xvB[3 * tb + 4], Bn2 = xvB[3 * tb + 5];

        const int wo = 12 * tb;

#define DO_STEP(ax, ay, az, bx, by, bz, j)                                   \
  {                                                                          \
    float a0, a1, a2, b0, b1, b2;                                            \
    j2_step(w1p, w2p, (ax), (ay), (az), SA, a0, a1, a2);                     \
    j2_step(w1p, w2p, (bx), (by), (bz), SB, b0, b1, b2);                     \
    DPP_BFLY6(a0, a1, a2, b0, b1, b2);                                       \
    float vA = (comp == 0) ? a0 : ((comp == 1) ? a1 : a2);                   \
    float vB = (comp == 0) ? b0 : ((comp == 1) ? b1 : b2);                   \
    float val = isA ? vA : vB;                                               \
    if (wact) wbase[wo + 3 * (j)] = val;                                     \
  }

        DO_STEP(A0.x, A0.y, A0.z,  B0.x, B0.y, B0.z, 0);
        DO_STEP(A0.w, A1.x, A1.y,  B0.w, B1.x, B1.y, 1);
        DO_STEP(A1.z, A1.w, A2.x,  B1.z, B1.w, B2.x, 2);
        DO_STEP(A2.y, A2.z, A2.w,  B2.y, B2.z, B2.w, 3);
#undef DO_STEP

        A0 = An0; A1 = An1; A2 = An2;
        B0 = Bn0; B1 = Bn1; B2 = Bn2;
    }

    __syncthreads();

    // ---- coalesced float4 flush LDS -> out ----
    {
        float4* og = (float4*)(out + blockBase);
        for (int i4 = tid; i4 < BPB * ROWF / 4; i4 += BLOCK) {
            int b  = i4 / (ROWF / 4);
            int r4 = i4 - b * (ROWF / 4);
            og[i4] = ((const float4*)(xs + b * ROWP))[r4];
        }
    }
}

extern "C" void kernel_launch(void* const* d_in, const int* in_sizes, int n_in,
                              void* d_out, int out_size, void* d_ws, size_t ws_size,
                              hipStream_t stream) {
    const float* x  = (const float*)d_in[0];
    const float* W1 = (const float*)d_in[1];
    const float* W2 = (const float*)d_in[2];
    float* out = (float*)d_out;

    const int B = 16384;
    dim3 grid(B / BPB);   // 256 blocks = 1 per CU
    dim3 block(BLOCK);
    prnn_j2_kernel<<<grid, block, 0, stream>>>(x, W1, W2, out);
}